// Round 14
// baseline (84.179 us; speedup 1.0000x reference)
//
#include <hip/hip_runtime.h>
#include <hip/hip_bf16.h>
#include <stdint.h>

// Problem constants: B=1, S=2048, H=1024, I=512, E=16, K=4
#define HH 1024
#define II 512
#define EE 16
#define TT 2048
#define KTOP 4
#define PP (TT * KTOP)      // 8192 routed pairs
#define MAXROWS 12288       // padded row capacity

typedef unsigned short u16;
typedef unsigned int u32;
typedef __attribute__((ext_vector_type(8))) short short8;       // bf16 MFMA A/B frag
typedef __attribute__((ext_vector_type(4))) float f32x4;        // MFMA C/D frag
typedef __attribute__((ext_vector_type(4))) unsigned short u16x4;
typedef __attribute__((ext_vector_type(8))) unsigned short u16x8;
typedef __attribute__((ext_vector_type(4))) unsigned int u32x4;

__device__ __forceinline__ u16 f2bf(float f) {  // fp32 -> bf16 RNE
  union { float f; unsigned u; } v; v.f = f;
  unsigned r = v.u + 0x7fffu + ((v.u >> 16) & 1u);
  return (u16)(r >> 16);
}
__device__ __forceinline__ float bf2f(u16 b) {
  union { unsigned u; float f; } v; v.u = ((unsigned)b) << 16; return v.f;
}
__device__ __forceinline__ u32 packbf(float lo, float hi) {
  return (u32)f2bf(lo) | ((u32)f2bf(hi) << 16);
}

// Direct global->LDS DMA, 16B per lane; dest wave-uniform base + lane*16.
__device__ __forceinline__ void gld16(const u16* g, u16* l) {
  __builtin_amdgcn_global_load_lds(
      (const __attribute__((address_space(1))) unsigned int*)g,
      (__attribute__((address_space(3))) unsigned int*)l, 16, 0, 0);
}

// ================= fused prep =================
// 641 blocks x 1024 threads:
//   block 0        : routing (16 waves)
//   blocks 1..128  : x fp32 -> bf16
//   blocks 129..640: Wg AND Wu transpose (one 128x128 tile of each, same coords),
//                    ALL 8 loads issued up front + sched_barrier(0) pin (fixes
//                    R13's VGPR=20 load serialization), double-buffered LDS.
union PLds {
  int s_e[PP];               // 32 KB routing state
  u32 t32[2][128][68];       // 69.6 KB transpose dbuf
};

__global__ __launch_bounds__(1024) void prep_fused(
    const float* __restrict__ x, const int* __restrict__ tidx,
    const float* __restrict__ tw,
    const float* __restrict__ wg, const float* __restrict__ wu,
    u16* __restrict__ xb, u16* __restrict__ WgT, u16* __restrict__ WuT,
    int* __restrict__ perm, float* __restrict__ wt, int* __restrict__ rowof,
    int* __restrict__ tile_e, int* __restrict__ tile_r,
    int* __restrict__ ntiles) {
  __shared__ PLds L;
  __shared__ int whist[16][16];
  __shared__ int wbase[16][16];
  __shared__ int pad_lo[EE], pad_hi[EE];

  const int bid = blockIdx.x;
  const int tid = threadIdx.x;

  if (bid == 0) {
    // ---------------- routing (16 waves x 512-pair segments) ----------------
    const int lane = tid & 63;
    const int wv = tid >> 6;

#pragma unroll
    for (int i = 0; i < 2; i++) {
      const int t = tid + i * 1024;
      const int4 v = ((const int4*)tidx)[t];
      const bool v0 = (v.x != v.y) && (v.x != v.z) && (v.x != v.w);
      const bool v1 = (v.y != v.z) && (v.y != v.w);
      const bool v2 = (v.z != v.w);
      L.s_e[t * 4 + 0] = v.x | (v0 ? 16 : 0);
      L.s_e[t * 4 + 1] = v.y | (v1 ? 16 : 0);
      L.s_e[t * 4 + 2] = v.z | (v2 ? 16 : 0);
      L.s_e[t * 4 + 3] = v.w | 16;
    }
    __syncthreads();

    int h0, h1, h2, h3, h4, h5, h6, h7, h8, h9, h10, h11, h12, h13, h14, h15;
    h0=h1=h2=h3=h4=h5=h6=h7=h8=h9=h10=h11=h12=h13=h14=h15=0;
    const unsigned long long ltm = (1ull << lane) - 1ull;
    for (int c = 0; c < 8; c++) {
      const int p = (wv << 9) + (c << 6) + lane;
      const int se = L.s_e[p];
      const int e = se & 15;
      const bool valid = (se & 16) != 0;
      int rank = 0;
#define RANK_STEP(J, HJ)                                            \
      {                                                             \
        unsigned long long m = __ballot(valid && (e == J));         \
        if (valid && (e == J)) rank = HJ + __popcll(m & ltm);       \
        HJ += __popcll(m);                                          \
      }
      RANK_STEP(0, h0)  RANK_STEP(1, h1)  RANK_STEP(2, h2)  RANK_STEP(3, h3)
      RANK_STEP(4, h4)  RANK_STEP(5, h5)  RANK_STEP(6, h6)  RANK_STEP(7, h7)
      RANK_STEP(8, h8)  RANK_STEP(9, h9)  RANK_STEP(10, h10) RANK_STEP(11, h11)
      RANK_STEP(12, h12) RANK_STEP(13, h13) RANK_STEP(14, h14) RANK_STEP(15, h15)
#undef RANK_STEP
      if (valid) L.s_e[p] = se | (rank << 16);
    }
    if (lane == 0) {
      whist[wv][0] = h0;   whist[wv][1] = h1;   whist[wv][2] = h2;   whist[wv][3] = h3;
      whist[wv][4] = h4;   whist[wv][5] = h5;   whist[wv][6] = h6;   whist[wv][7] = h7;
      whist[wv][8] = h8;   whist[wv][9] = h9;   whist[wv][10] = h10; whist[wv][11] = h11;
      whist[wv][12] = h12; whist[wv][13] = h13; whist[wv][14] = h14; whist[wv][15] = h15;
    }
    __syncthreads();

    if (tid == 0) {
      int off = 0, nt = 0;
      for (int j = 0; j < EE; j++) {
        int tot = 0;
        for (int w = 0; w < 16; w++) { wbase[w][j] = off + tot; tot += whist[w][j]; }
        const int cap = (tot + 127) & ~127;
        pad_lo[j] = off + tot;
        pad_hi[j] = off + cap;
        for (int m0 = 0; m0 < cap; m0 += 128) { tile_e[nt] = j; tile_r[nt] = off + m0; nt++; }
        off += cap;
      }
      *ntiles = nt;
    }
    __syncthreads();

#pragma unroll
    for (int i = 0; i < 8; i++) {
      const int p = i * 1024 + tid;
      const int se = L.s_e[p];
      int pos = -1;
      if (se & 16) {
        const int e = se & 15;
        const int r = se >> 16;
        pos = wbase[p >> 9][e] + r;
        perm[pos] = p >> 2;
        wt[pos] = tw[p];
      }
      rowof[p] = pos;
    }
    for (int j = 0; j < EE; j++) {
      const int lo = pad_lo[j], hi = pad_hi[j];
      for (int i = lo + tid; i < hi; i += 1024) {
        perm[i] = 0;          // pad: token 0 with weight 0 contributes nothing
        wt[i] = 0.f;
      }
    }
    return;
  }

  if (bid <= 128) {
    // ---------------- x fp32 -> bf16, 16 elems/thread ----------------
    const int base = ((bid - 1) * 1024 + tid) * 16;
    f32x4 v0 = *(const f32x4*)(x + base);
    f32x4 v1 = *(const f32x4*)(x + base + 4);
    f32x4 v2 = *(const f32x4*)(x + base + 8);
    f32x4 v3 = *(const f32x4*)(x + base + 12);
    u16x8 o0 = { f2bf(v0[0]), f2bf(v0[1]), f2bf(v0[2]), f2bf(v0[3]),
                 f2bf(v1[0]), f2bf(v1[1]), f2bf(v1[2]), f2bf(v1[3]) };
    u16x8 o1 = { f2bf(v2[0]), f2bf(v2[1]), f2bf(v2[2]), f2bf(v2[3]),
                 f2bf(v3[0]), f2bf(v3[1]), f2bf(v3[2]), f2bf(v3[3]) };
    *(u16x8*)(xb + base) = o0;
    *(u16x8*)(xb + base + 8) = o1;
    return;
  }

  // ---------------- Wg + Wu transpose: one 128x128 tile of EACH ----------------
  const int pb = bid - 129;              // 0..511
  const int zz = pb >> 5;                // expert
  const int sub = pb & 31;
  const int xi = sub & 3, yi = sub >> 2;
  const size_t mat = (size_t)zz * HH * II;
  const int r0 = yi * 128, c0 = xi * 128;

  const int rp = tid >> 4, cq8 = (tid & 15) * 8;
  const size_t soff = mat + (size_t)(r0 + 2 * rp) * II + c0 + cq8;
  const float* sp0 = wg + soff;
  const float* sp1 = wu + soff;
  const f32x4 a0 = *(const f32x4*)(sp0);
  const f32x4 a1 = *(const f32x4*)(sp0 + 4);
  const f32x4 b0 = *(const f32x4*)(sp0 + II);
  const f32x4 b1 = *(const f32x4*)(sp0 + II + 4);
  const f32x4 e0 = *(const f32x4*)(sp1);
  const f32x4 e1 = *(const f32x4*)(sp1 + 4);
  const f32x4 g0 = *(const f32x4*)(sp1 + II);
  const f32x4 g1 = *(const f32x4*)(sp1 + II + 4);
  __builtin_amdgcn_sched_barrier(0);     // pin: all 8 loads issued before first use

  const int key = tid & 15;
  const int rpx = rp ^ ((key & 7) << 3) ^ (((key >> 2) & 1) << 2);
  // read-phase coords
  const int c = tid >> 3, q = tid & 7;
  const int rkey = c >> 3;
  const int qb = (q ^ (rkey & 7)) * 8;
  const int b2 = ((rkey >> 2) & 1) * 4;
  const size_t doff = mat + (size_t)(c0 + c) * HH + r0 + q * 16;

#pragma unroll
  for (int j = 0; j < 4; j++) L.t32[0][cq8 + j][rpx] = packbf(a0[j], b0[j]);
#pragma unroll
  for (int j = 0; j < 4; j++) L.t32[0][cq8 + 4 + j][rpx] = packbf(a1[j], b1[j]);
  __syncthreads();
  // wu writes (buf1) overlap wg reads (buf0)
#pragma unroll
  for (int j = 0; j < 4; j++) L.t32[1][cq8 + j][rpx] = packbf(e0[j], g0[j]);
#pragma unroll
  for (int j = 0; j < 4; j++) L.t32[1][cq8 + 4 + j][rpx] = packbf(e1[j], g1[j]);
  {
    u32x4 v0, v1;
#pragma unroll
    for (int j = 0; j < 4; j++) v0[j] = L.t32[0][c][qb + b2 + j];
#pragma unroll
    for (int j = 0; j < 4; j++) v1[j] = L.t32[0][c][qb + (b2 ^ 4) + j];
    u16* dp = WgT + doff;
    *(u32x4*)(dp) = v0;
    *(u32x4*)(dp + 8) = v1;
  }
  __syncthreads();
  {
    u32x4 v0, v1;
#pragma unroll
    for (int j = 0; j < 4; j++) v0[j] = L.t32[1][c][qb + b2 + j];
#pragma unroll
    for (int j = 0; j < 4; j++) v1[j] = L.t32[1][c][qb + (b2 ^ 4) + j];
    u16* dp = WuT + doff;
    *(u32x4*)(dp) = v0;
    *(u32x4*)(dp + 8) = v1;
  }
}

// ---------------- GEMM1 (+ embedded Wd transpose blocks) ----------------
// blockIdx.y < 80 : GEMM tile 128(M) x 64(N), BK=64, 4 waves 2x2 (R12 form).
// blockIdx.y >= 80: Wd transpose, 128(i) x 64(h) fp32 tile -> WdT bf16.
// Both branches share one 32 KB SMEM allocation (block-uniform branch).
__global__ __launch_bounds__(256) void gemm1_kernel(
    const u16* __restrict__ xb, const u16* __restrict__ WgT, const u16* __restrict__ WuT,
    const float* __restrict__ wd, u16* __restrict__ WdT,
    const int* __restrict__ perm, const float* __restrict__ wt,
    const int* __restrict__ tile_e, const int* __restrict__ tile_r,
    const int* __restrict__ ntiles, u16* __restrict__ ACT) {
  __shared__ __align__(16) u16 SMEM[16384];   // 32 KB, unioned across branches
  const int tid = threadIdx.x;

  if (blockIdx.y >= 80) {
    // ---- Wd transpose: tile 128 rows(i) x 64 cols(h) ----
    const int pb = (blockIdx.y - 80) * 8 + blockIdx.x;   // 0..1023
    const int zz = pb >> 6;
    const int sub = pb & 63;
    const int r0 = (sub >> 4) * 128;     // i
    const int c0 = (sub & 15) * 64;      // h
    const size_t mat = (size_t)zz * II * HH;
    u32 (*T32)[68] = (u32(*)[68])SMEM;   // [64 cols][68 rowpairs], 17.4 KB

    const int rpA = tid >> 3;            // 0..31 (pass B: +32)
    const int cq8 = (tid & 7) * 8;
    const float* spA = wd + mat + (size_t)(r0 + 2 * rpA) * HH + c0 + cq8;
    const float* spB = spA + (size_t)64 * HH;
    const f32x4 a0 = *(const f32x4*)(spA);
    const f32x4 a1 = *(const f32x4*)(spA + 4);
    const f32x4 b0 = *(const f32x4*)(spA + HH);
    const f32x4 b1 = *(const f32x4*)(spA + HH + 4);
    const f32x4 e0 = *(const f32x4*)(spB);
    const f32x4 e1 = *(const f32x4*)(spB + 4);
    const f32x4 g0 = *(const f32x4*)(spB + HH);
    const f32x4 g1 = *(const f32x4*)(spB + HH + 4);
    __builtin_amdgcn_sched_barrier(0);   // pin: all 8 loads issued up front

    const int key = tid & 7;             // = col>>3 for this thread's octet
    const int sw = ((key & 7) << 3) ^ (((key >> 2) & 1) << 2);
    const int rpxA = rpA ^ sw;
    const int rpxB = (rpA + 32) ^ sw;
#pragma unroll
    for (int j = 0; j < 4; j++) T32[cq8 + j][rpxA] = packbf(a0[j], b0[j]);
#pragma unroll
    for (int j = 0; j < 4; j++) T32[cq8 + 4 + j][rpxA] = packbf(a1[j], b1[j]);
#pragma unroll
    for (int j = 0; j < 4; j++) T32[cq8 + j][rpxB] = packbf(e0[j], g0[j]);
#pragma unroll
    for (int j = 0; j < 4; j++) T32[cq8 + 4 + j][rpxB] = packbf(e1[j], g1[j]);
    __syncthreads();

    const int c = tid >> 2;              // out row (h) 0..63
    const int q2 = tid & 3;
    const int rkey = c >> 3;             // 0..7
    const int b2 = ((rkey >> 2) & 1) * 4;
#pragma unroll
    for (int pass = 0; pass < 2; pass++) {
      const int o = q2 + pass * 4;       // rowpair octet 0..7
      const int qb = (o ^ (rkey & 7)) * 8;
      u32x4 v0, v1;
#pragma unroll
      for (int j = 0; j < 4; j++) v0[j] = T32[c][qb + b2 + j];
#pragma unroll
      for (int j = 0; j < 4; j++) v1[j] = T32[c][qb + (b2 ^ 4) + j];
      u16* dp = WdT + mat + (size_t)(c0 + c) * II + r0 + o * 16;
      *(u32x4*)(dp) = v0;
      *(u32x4*)(dp + 8) = v1;
    }
    return;
  }

  // ---- GEMM branch (R12-verified form) ----
  const int tileid = blockIdx.y;
  if (tileid >= *ntiles) return;
  const int e = tile_e[tileid];
  const int row0 = tile_r[tileid];
  const int n0 = blockIdx.x * 64;

  u16* const As = SMEM;                  // 128*64
  u16* const Gs = SMEM + 8192;           // 64*64
  u16* const Us = SMEM + 12288;          // 64*64

  const int lane = tid & 63;
  const int wid = tid >> 6;
  const int wm = wid >> 1, wn = wid & 1;
  const int fr = lane & 15, fq = lane >> 4;

  const int lrow = lane >> 3;
  const int sc8 = ((lane & 7) ^ lrow) * 8;   // pre-swizzled global chunk

  const u16* gA[4]; u16* lA[4];
#pragma unroll
  for (int j = 0; j < 4; j++) {
    const int trow = j * 32 + wid * 8 + lrow;
    gA[j] = xb + (size_t)perm[row0 + trow] * HH + sc8;
    lA[j] = As + (j * 4 + wid) * 512;
  }
  const u16 *gG[2], *gU[2];
  u16 *lG[2], *lU[2];
#pragma unroll
  for (int j = 0; j < 2; j++) {
    const int nrow = j * 32 + wid * 8 + lrow;
    gG[j] = WgT + ((size_t)e * II + n0 + nrow) * HH + sc8;
    gU[j] = WuT + ((size_t)e * II + n0 + nrow) * HH + sc8;
    lG[j] = Gs + (j * 4 + wid) * 512;
    lU[j] = Us + (j * 4 + wid) * 512;
  }

  f32x4 accg[4][2], accu[4][2];
  const f32x4 vz = {0.f, 0.f, 0.f, 0.f};
#pragma unroll
  for (int m = 0; m < 4; m++)
#pragma unroll
    for (int n = 0; n < 2; n++) { accg[m][n] = vz; accu[m][n] = vz; }

  for (int k0 = 0; k0 < HH; k0 += 64) {
    __syncthreads();
#pragma unroll
    for (int j = 0; j < 4; j++) gld16(gA[j] + k0, lA[j]);
#pragma unroll
    for (int j = 0; j < 2; j++) { gld16(gG[j] + k0, lG[j]); gld16(gU[j] + k0, lU[j]); }
    __syncthreads();

#pragma unroll
    for (int ks = 0; ks < 2; ks++) {
      short8 af[4], bg[2], bu[2];
#pragma unroll
      for (int m = 0; m < 4; m++) {
        const int r = wm * 64 + m * 16 + fr;
        af[m] = *(const short8*)(&As[r * 64 + (((ks * 4 + fq) ^ (r & 7)) * 8)]);
      }
#pragma unroll
      for (int n = 0; n < 2; n++) {
        const int r = wn * 32 + n * 16 + fr;
        bg[n] = *(const short8*)(&Gs[r * 64 + (((ks * 4 + fq) ^ (r & 7)) * 8)]);
        bu[n] = *(const short8*)(&Us[r * 64 + (((ks * 4 + fq) ^ (r & 7)) * 8)]);
      }
#pragma unroll
      for (int m = 0; m < 4; m++)
#pragma unroll
        for (int n = 0; n < 2; n++) {
          accg[m][n] = __builtin_amdgcn_mfma_f32_16x16x32_bf16(af[m], bg[n], accg[m][n], 0, 0, 0);
          accu[m][n] = __builtin_amdgcn_mfma_f32_16x16x32_bf16(af[m], bu[n], accu[m][n], 0, 0, 0);
        }
    }
  }

  // C/D: col = lane&15, row = fq*4 + j within each 16-row m-frag
#pragma unroll
  for (int m = 0; m < 4; m++) {
    const int rbase = wm * 64 + m * 16 + fq * 4;
#pragma unroll
    for (int j = 0; j < 4; j++) {
      const int rloc = rbase + j;
      const float w = wt[row0 + rloc];
#pragma unroll
      for (int n = 0; n < 2; n++) {
        const float g = accg[m][n][j];
        const float u = accu[m][n][j];
        const float s = g / (1.f + __expf(-g));   // silu
        ACT[(size_t)(row0 + rloc) * II + n0 + (wn * 32 + n * 16 + fr)] = f2bf(s * u * w);
      }
    }
  }
}

// ---------------- GEMM2: D[row][h] = ACT @ Wd ----------------
// Tile 128(M) x 128(N), BK=64, 4 waves as 2x2; gld16 staging (R12 form).
__global__ __launch_bounds__(256) void gemm2_kernel(
    const u16* __restrict__ ACT, const u16* __restrict__ WdT,
    const int* __restrict__ tile_e, const int* __restrict__ tile_r,
    const int* __restrict__ ntiles, u16* __restrict__ D) {
  const int tileid = blockIdx.y;
  if (tileid >= *ntiles) return;
  const int e = tile_e[tileid];
  const int row0 = tile_r[tileid];
  const int n0 = blockIdx.x * 128;

  __shared__ __align__(16) u16 As[128 * 64];   // 16 KB
  __shared__ __align__(16) u16 Bs[128 * 64];   // 16 KB

  const int tid = threadIdx.x;
  const int lane = tid & 63;
  const int wid = tid >> 6;
  const int wm = wid >> 1, wn = wid & 1;
  const int fr = lane & 15, fq = lane >> 4;

  const int lrow = lane >> 3;
  const int sc8 = ((lane & 7) ^ lrow) * 8;

  const u16 *gA[4], *gB[4];
  u16 *lA[4], *lB[4];
#pragma unroll
  for (int j = 0; j < 4; j++) {
    const int trow = j * 32 + wid * 8 + lrow;
    gA[j] = ACT + (size_t)(row0 + trow) * II + sc8;
    gB[j] = WdT + ((size_t)e * HH + n0 + trow) * II + sc8;
    lA[j] = As + (j * 4 + wid) * 512;
    lB[j] = Bs + (j * 4 + wid) * 512;
  }

  f32x4 acc[4][4];
  const f32x4 vz = {0.f, 0.f, 0.f, 0.f};
#pragma unroll
  for (int m = 0; m < 4; m++)
#pragma unroll
    for (int n = 0; n < 4; n++) acc[m][n] = vz;

  for (int k0 = 0; k0 < II; k0 += 64) {
    __syncthreads();
#pragma unroll
    for (int j = 0; j < 4; j++) { gld16(gA[j] + k0, lA[j]); gld16(gB[j] + k0, lB[j]); }
    __syncthreads();

#pragma unroll
    for (int ks = 0; ks < 2; ks++) {
      short8 af[4], bf[4];
#pragma unroll
      for (int m = 0; m < 4; m++) {
        const int r = wm * 64 + m * 16 + fr;
        af[m] = *(const short8*)(&As[r * 64 + (((ks * 4 + fq) ^ (r & 7)) * 8)]);
      }
#pragma unroll
      for (int n = 0; n < 4; n++) {
        const int r = wn * 64 + n * 16 + fr;
        bf[n] = *(const short8*)(&Bs[r * 64 + (((ks * 4 + fq) ^ (r & 7)) * 8)]);
      }
#pragma unroll
      for (int m = 0; m < 4; m++)
#pragma unroll
        for (int n = 0; n < 4; n++)
          acc[m][n] = __builtin_amdgcn_mfma_f32_16x16x32_bf16(af[m], bf[n], acc[m][n], 0, 0, 0);
    }
  }

#pragma unroll
  for (int m = 0; m < 4; m++) {
    const int rbase = wm * 64 + m * 16 + fq * 4;
#pragma unroll
    for (int j = 0; j < 4; j++) {
      u16* dp = D + (size_t)(row0 + rbase + j) * HH + n0 + wn * 64 + fr;
#pragma unroll
      for (int n = 0; n < 4; n++)
        dp[n * 16] = f2bf(acc[m][n][j]);
    }
  }
}

// ---------------- combine: out[t][h] = sum over t's valid pairs of D[row][h] ----------------
__global__ __launch_bounds__(256) void combine_kernel(
    const u16* __restrict__ D, const int* __restrict__ rowof,
    float* __restrict__ out) {
  const int t = blockIdx.x;
  const int h = threadIdx.x * 4;
  const int4 r4 = ((const int4*)rowof)[t];
  float a0 = 0.f, a1 = 0.f, a2 = 0.f, a3 = 0.f;
#define ACCUM(R)                                                     \
  if ((R) >= 0) {                                                    \
    u16x4 d = *(const u16x4*)(D + (size_t)(R) * HH + h);             \
    a0 += bf2f(d[0]); a1 += bf2f(d[1]); a2 += bf2f(d[2]); a3 += bf2f(d[3]); \
  }
  ACCUM(r4.x) ACCUM(r4.y) ACCUM(r4.z) ACCUM(r4.w)
#undef ACCUM
  float4 o = { a0, a1, a2, a3 };
  *(float4*)(out + (size_t)t * HH + h) = o;
}

// ---------------- launch ----------------
extern "C" void kernel_launch(void* const* d_in, const int* in_sizes, int n_in,
                              void* d_out, int out_size, void* d_ws, size_t ws_size,
                              hipStream_t stream) {
  const float* x = (const float*)d_in[0];
  const int* tidx = (const int*)d_in[1];
  const float* tw = (const float*)d_in[2];
  const float* wg = (const float*)d_in[3];
  const float* wu = (const float*)d_in[4];
  const float* wd = (const float*)d_in[5];
  float* out = (float*)d_out;

  // ws layout (bytes); D overlays WgT/WuT (dead after gemm1).
  char* ws = (char*)d_ws;
  int* ntiles = (int*)(ws + 0);
  int* tile_e = (int*)(ws + 1024);
  int* tile_r = (int*)(ws + 2048);
  int* perm = (int*)(ws + 4096);                 // 12288 ints
  float* wt = (float*)(ws + 53248);              // 12288 floats
  int* rowof = (int*)(ws + 102400);              // 8192 ints
  u16* xb = (u16*)(ws + 262144);                 // [2048][1024] bf16, 4 MB
  u16* WgT = (u16*)(ws + 4456448);               // [E][I][H] bf16, 16.78 MB
  u16* WuT = (u16*)(ws + 21233664);              // [E][I][H] bf16, 16.78 MB
  u16* WdT = (u16*)(ws + 38010880);              // [E][H][I] bf16, 16.78 MB
  u16* ACT = (u16*)(ws + 54788096);              // [MAXROWS][I] bf16, 12.58 MB
  u16* D = (u16*)(ws + 4456448);                 // [MAXROWS][H] bf16, 25.2 MB (overlay)

  prep_fused<<<641, 1024, 0, stream>>>(x, tidx, tw, wg, wu,
                                       xb, WgT, WuT,
                                       perm, wt, rowof, tile_e, tile_r, ntiles);
  gemm1_kernel<<<dim3(8, 208), 256, 0, stream>>>(xb, WgT, WuT, wd, WdT, perm, wt,
                                                 tile_e, tile_r, ntiles, ACT);
  gemm2_kernel<<<dim3(HH / 128, 80), 256, 0, stream>>>(ACT, WdT,
                                                       tile_e, tile_r, ntiles, D);
  combine_kernel<<<TT, 256, 0, stream>>>(D, rowof, out);
}

// Round 15
// 78.978 us; speedup vs baseline: 1.0658x; 1.0658x over previous
//
#include <hip/hip_runtime.h>
#include <hip/hip_bf16.h>
#include <stdint.h>

// Problem constants: B=1, S=2048, H=1024, I=512, E=16, K=4
#define HH 1024
#define II 512
#define EE 16
#define TT 2048
#define KTOP 4
#define PP (TT * KTOP)      // 8192 routed pairs
#define MAXROWS 12288       // padded row capacity

typedef unsigned short u16;
typedef unsigned int u32;
typedef __attribute__((ext_vector_type(8))) short short8;       // bf16 MFMA A/B frag
typedef __attribute__((ext_vector_type(4))) float f32x4;        // MFMA C/D frag
typedef __attribute__((ext_vector_type(4))) unsigned short u16x4;
typedef __attribute__((ext_vector_type(8))) unsigned short u16x8;
typedef __attribute__((ext_vector_type(4))) unsigned int u32x4;

__device__ __forceinline__ u16 f2bf(float f) {  // fp32 -> bf16 RNE
  union { float f; unsigned u; } v; v.f = f;
  unsigned r = v.u + 0x7fffu + ((v.u >> 16) & 1u);
  return (u16)(r >> 16);
}
__device__ __forceinline__ float bf2f(u16 b) {
  union { unsigned u; float f; } v; v.u = ((unsigned)b) << 16; return v.f;
}
__device__ __forceinline__ u32 packbf(float lo, float hi) {
  return (u32)f2bf(lo) | ((u32)f2bf(hi) << 16);
}

// Direct global->LDS DMA, 16B per lane; dest wave-uniform base + lane*16.
__device__ __forceinline__ void gld16(const u16* g, u16* l) {
  __builtin_amdgcn_global_load_lds(
      (const __attribute__((address_space(1))) unsigned int*)g,
      (__attribute__((address_space(3))) unsigned int*)l, 16, 0, 0);
}

// ================= fused prep =================
// 897 blocks x 1024 threads:
//   block 0        : routing (16 waves, proven form)
//   blocks 1..128  : x fp32 -> bf16
//   blocks 129..896: 4-team transpose; team (tid>>8) transposes one 128x64 fp32
//                    tile from the flat list {Wg:0..1023, Wu:1024..2047,
//                    Wd:2048..3071}. All 8 loads up-front + sched_barrier pin;
//                    swizzled [64][68] LDS (write 2-way, read contiguous).
union PLds {
  int s_e[PP];               // 32 KB routing state
  u32 t4[4][64][68];         // 69.6 KB: 4 team transpose tiles
};

__global__ __launch_bounds__(1024) void prep_fused(
    const float* __restrict__ x, const int* __restrict__ tidx,
    const float* __restrict__ tw,
    const float* __restrict__ wg, const float* __restrict__ wu,
    const float* __restrict__ wd,
    u16* __restrict__ xb, u16* __restrict__ WgT, u16* __restrict__ WuT,
    u16* __restrict__ WdT,
    int* __restrict__ perm, float* __restrict__ wt, int* __restrict__ rowof,
    int* __restrict__ tile_e, int* __restrict__ tile_r,
    int* __restrict__ ntiles) {
  __shared__ PLds L;
  __shared__ int whist[16][16];
  __shared__ int wbase[16][16];
  __shared__ int pad_lo[EE], pad_hi[EE];

  const int bid = blockIdx.x;
  const int tid = threadIdx.x;

  if (bid == 0) {
    // ---------------- routing (16 waves x 512-pair segments) ----------------
    const int lane = tid & 63;
    const int wv = tid >> 6;

#pragma unroll
    for (int i = 0; i < 2; i++) {
      const int t = tid + i * 1024;
      const int4 v = ((const int4*)tidx)[t];
      const bool v0 = (v.x != v.y) && (v.x != v.z) && (v.x != v.w);
      const bool v1 = (v.y != v.z) && (v.y != v.w);
      const bool v2 = (v.z != v.w);
      L.s_e[t * 4 + 0] = v.x | (v0 ? 16 : 0);
      L.s_e[t * 4 + 1] = v.y | (v1 ? 16 : 0);
      L.s_e[t * 4 + 2] = v.z | (v2 ? 16 : 0);
      L.s_e[t * 4 + 3] = v.w | 16;
    }
    __syncthreads();

    int h0, h1, h2, h3, h4, h5, h6, h7, h8, h9, h10, h11, h12, h13, h14, h15;
    h0=h1=h2=h3=h4=h5=h6=h7=h8=h9=h10=h11=h12=h13=h14=h15=0;
    const unsigned long long ltm = (1ull << lane) - 1ull;
    for (int c = 0; c < 8; c++) {
      const int p = (wv << 9) + (c << 6) + lane;
      const int se = L.s_e[p];
      const int e = se & 15;
      const bool valid = (se & 16) != 0;
      int rank = 0;
#define RANK_STEP(J, HJ)                                            \
      {                                                             \
        unsigned long long m = __ballot(valid && (e == J));         \
        if (valid && (e == J)) rank = HJ + __popcll(m & ltm);       \
        HJ += __popcll(m);                                          \
      }
      RANK_STEP(0, h0)  RANK_STEP(1, h1)  RANK_STEP(2, h2)  RANK_STEP(3, h3)
      RANK_STEP(4, h4)  RANK_STEP(5, h5)  RANK_STEP(6, h6)  RANK_STEP(7, h7)
      RANK_STEP(8, h8)  RANK_STEP(9, h9)  RANK_STEP(10, h10) RANK_STEP(11, h11)
      RANK_STEP(12, h12) RANK_STEP(13, h13) RANK_STEP(14, h14) RANK_STEP(15, h15)
#undef RANK_STEP
      if (valid) L.s_e[p] = se | (rank << 16);
    }
    if (lane == 0) {
      whist[wv][0] = h0;   whist[wv][1] = h1;   whist[wv][2] = h2;   whist[wv][3] = h3;
      whist[wv][4] = h4;   whist[wv][5] = h5;   whist[wv][6] = h6;   whist[wv][7] = h7;
      whist[wv][8] = h8;   whist[wv][9] = h9;   whist[wv][10] = h10; whist[wv][11] = h11;
      whist[wv][12] = h12; whist[wv][13] = h13; whist[wv][14] = h14; whist[wv][15] = h15;
    }
    __syncthreads();

    if (tid == 0) {
      int off = 0, nt = 0;
      for (int j = 0; j < EE; j++) {
        int tot = 0;
        for (int w = 0; w < 16; w++) { wbase[w][j] = off + tot; tot += whist[w][j]; }
        const int cap = (tot + 127) & ~127;
        pad_lo[j] = off + tot;
        pad_hi[j] = off + cap;
        for (int m0 = 0; m0 < cap; m0 += 128) { tile_e[nt] = j; tile_r[nt] = off + m0; nt++; }
        off += cap;
      }
      *ntiles = nt;
    }
    __syncthreads();

#pragma unroll
    for (int i = 0; i < 8; i++) {
      const int p = i * 1024 + tid;
      const int se = L.s_e[p];
      int pos = -1;
      if (se & 16) {
        const int e = se & 15;
        const int r = se >> 16;
        pos = wbase[p >> 9][e] + r;
        perm[pos] = p >> 2;
        wt[pos] = tw[p];
      }
      rowof[p] = pos;
    }
    for (int j = 0; j < EE; j++) {
      const int lo = pad_lo[j], hi = pad_hi[j];
      for (int i = lo + tid; i < hi; i += 1024) {
        perm[i] = 0;          // pad: token 0 with weight 0 contributes nothing
        wt[i] = 0.f;
      }
    }
    return;
  }

  if (bid <= 128) {
    // ---------------- x fp32 -> bf16, 16 elems/thread ----------------
    const int base = ((bid - 1) * 1024 + tid) * 16;
    f32x4 v0 = *(const f32x4*)(x + base);
    f32x4 v1 = *(const f32x4*)(x + base + 4);
    f32x4 v2 = *(const f32x4*)(x + base + 8);
    f32x4 v3 = *(const f32x4*)(x + base + 12);
    u16x8 o0 = { f2bf(v0[0]), f2bf(v0[1]), f2bf(v0[2]), f2bf(v0[3]),
                 f2bf(v1[0]), f2bf(v1[1]), f2bf(v1[2]), f2bf(v1[3]) };
    u16x8 o1 = { f2bf(v2[0]), f2bf(v2[1]), f2bf(v2[2]), f2bf(v2[3]),
                 f2bf(v3[0]), f2bf(v3[1]), f2bf(v3[2]), f2bf(v3[3]) };
    *(u16x8*)(xb + base) = o0;
    *(u16x8*)(xb + base + 8) = o1;
    return;
  }

  // ---------------- 4-team transpose: one 128(r) x 64(c) fp32 tile per team ----------------
  const int team = tid >> 8;             // 0..3
  const int t = tid & 255;
  const int g = (bid - 129) * 4 + team;  // global tile 0..3071
  const int matsel = g >> 10;
  const int w = g & 1023;
  const int zz = w >> 6;                 // expert
  const int sub = w & 63;
  const float* src; u16* dst; int C, Rout, r0, c0;
  if (matsel == 0)      { src = wg; dst = WgT; C = II; Rout = HH; r0 = (sub >> 3) * 128; c0 = (sub & 7) * 64; }
  else if (matsel == 1) { src = wu; dst = WuT; C = II; Rout = HH; r0 = (sub >> 3) * 128; c0 = (sub & 7) * 64; }
  else                  { src = wd; dst = WdT; C = HH; Rout = II; r0 = (sub >> 4) * 128; c0 = (sub & 15) * 64; }
  const size_t mat = (size_t)zz * HH * II;   // same element count for all 3
  u32 (*T32)[68] = L.t4[team];

  // load phase: thread (rpA = rowpair 0..31 [+32 for B], cq8 = col octet)
  const int rpA = t >> 3;
  const int cq8 = (t & 7) * 8;
  const float* spA = src + mat + (size_t)(r0 + 2 * rpA) * C + c0 + cq8;
  const float* spB = spA + (size_t)64 * C;
  const f32x4 a0 = *(const f32x4*)(spA);
  const f32x4 a1 = *(const f32x4*)(spA + 4);
  const f32x4 b0 = *(const f32x4*)(spA + C);
  const f32x4 b1 = *(const f32x4*)(spA + C + 4);
  const f32x4 e0 = *(const f32x4*)(spB);
  const f32x4 e1 = *(const f32x4*)(spB + 4);
  const f32x4 g0 = *(const f32x4*)(spB + HH * 0 + C);
  const f32x4 g1 = *(const f32x4*)(spB + C + 4);
  __builtin_amdgcn_sched_barrier(0);     // pin: all 8 loads issued before first use

  const int key = t & 7;                 // = col>>3 for this thread's octet
  const int sw = ((key & 7) << 3) ^ (((key >> 2) & 1) << 2);
  const int rpxA = rpA ^ sw;
  const int rpxB = (rpA + 32) ^ sw;
#pragma unroll
  for (int j = 0; j < 4; j++) T32[cq8 + j][rpxA] = packbf(a0[j], b0[j]);
#pragma unroll
  for (int j = 0; j < 4; j++) T32[cq8 + 4 + j][rpxA] = packbf(a1[j], b1[j]);
#pragma unroll
  for (int j = 0; j < 4; j++) T32[cq8 + j][rpxB] = packbf(e0[j], g0[j]);
#pragma unroll
  for (int j = 0; j < 4; j++) T32[cq8 + 4 + j][rpxB] = packbf(e1[j], g1[j]);
  __syncthreads();                       // block-wide; every team hits exactly once

  // read+store phase: thread (c = out row 0..63, q2 = 0..3; two passes)
  const int c = t >> 2;
  const int q2 = t & 3;
  const int rkey = c >> 3;               // 0..7
  const int b2 = ((rkey >> 2) & 1) * 4;
#pragma unroll
  for (int pass = 0; pass < 2; pass++) {
    const int o = q2 + pass * 4;         // rowpair octet 0..7
    const int qb = (o ^ (rkey & 7)) * 8;
    u32x4 v0, v1;
#pragma unroll
    for (int j = 0; j < 4; j++) v0[j] = T32[c][qb + b2 + j];
#pragma unroll
    for (int j = 0; j < 4; j++) v1[j] = T32[c][qb + (b2 ^ 4) + j];
    u16* dp = dst + mat + (size_t)(c0 + c) * Rout + r0 + o * 16;
    *(u32x4*)(dp) = v0;
    *(u32x4*)(dp + 8) = v1;
  }
}

// ---------------- GEMM1: ACT[r][i] = silu(x@Wg) * (x@Wu) * gate_weight ----------------
// Tile 128(M) x 64(N), BK=64, 4 waves as 2x2. gld16 staging (R12/R13-verified).
__global__ __launch_bounds__(256) void gemm1_kernel(
    const u16* __restrict__ xb, const u16* __restrict__ WgT, const u16* __restrict__ WuT,
    const int* __restrict__ perm, const float* __restrict__ wt,
    const int* __restrict__ tile_e, const int* __restrict__ tile_r,
    const int* __restrict__ ntiles, u16* __restrict__ ACT) {
  const int tileid = blockIdx.y;
  if (tileid >= *ntiles) return;
  const int e = tile_e[tileid];
  const int row0 = tile_r[tileid];
  const int n0 = blockIdx.x * 64;

  __shared__ __align__(16) u16 As[128 * 64];   // 16 KB
  __shared__ __align__(16) u16 Gs[64 * 64];    // 8 KB
  __shared__ __align__(16) u16 Us[64 * 64];    // 8 KB

  const int tid = threadIdx.x;
  const int lane = tid & 63;
  const int wid = tid >> 6;
  const int wm = wid >> 1, wn = wid & 1;
  const int fr = lane & 15, fq = lane >> 4;

  const int lrow = lane >> 3;            // 0..7: row within 8-row group
  const int sc8 = ((lane & 7) ^ lrow) * 8;  // pre-swizzled global chunk (u16 units)

  const u16* gA[4]; u16* lA[4];
#pragma unroll
  for (int j = 0; j < 4; j++) {
    const int trow = j * 32 + wid * 8 + lrow;
    gA[j] = xb + (size_t)perm[row0 + trow] * HH + sc8;
    lA[j] = As + (j * 4 + wid) * 512;
  }
  const u16 *gG[2], *gU[2];
  u16 *lG[2], *lU[2];
#pragma unroll
  for (int j = 0; j < 2; j++) {
    const int nrow = j * 32 + wid * 8 + lrow;
    gG[j] = WgT + ((size_t)e * II + n0 + nrow) * HH + sc8;
    gU[j] = WuT + ((size_t)e * II + n0 + nrow) * HH + sc8;
    lG[j] = Gs + (j * 4 + wid) * 512;
    lU[j] = Us + (j * 4 + wid) * 512;
  }

  f32x4 accg[4][2], accu[4][2];
  const f32x4 vz = {0.f, 0.f, 0.f, 0.f};
#pragma unroll
  for (int m = 0; m < 4; m++)
#pragma unroll
    for (int n = 0; n < 2; n++) { accg[m][n] = vz; accu[m][n] = vz; }

  for (int k0 = 0; k0 < HH; k0 += 64) {
    __syncthreads();
#pragma unroll
    for (int j = 0; j < 4; j++) gld16(gA[j] + k0, lA[j]);
#pragma unroll
    for (int j = 0; j < 2; j++) { gld16(gG[j] + k0, lG[j]); gld16(gU[j] + k0, lU[j]); }
    __syncthreads();

#pragma unroll
    for (int ks = 0; ks < 2; ks++) {
      short8 af[4], bg[2], bu[2];
#pragma unroll
      for (int m = 0; m < 4; m++) {
        const int r = wm * 64 + m * 16 + fr;
        af[m] = *(const short8*)(&As[r * 64 + (((ks * 4 + fq) ^ (r & 7)) * 8)]);
      }
#pragma unroll
      for (int n = 0; n < 2; n++) {
        const int r = wn * 32 + n * 16 + fr;
        bg[n] = *(const short8*)(&Gs[r * 64 + (((ks * 4 + fq) ^ (r & 7)) * 8)]);
        bu[n] = *(const short8*)(&Us[r * 64 + (((ks * 4 + fq) ^ (r & 7)) * 8)]);
      }
#pragma unroll
      for (int m = 0; m < 4; m++)
#pragma unroll
        for (int n = 0; n < 2; n++) {
          accg[m][n] = __builtin_amdgcn_mfma_f32_16x16x32_bf16(af[m], bg[n], accg[m][n], 0, 0, 0);
          accu[m][n] = __builtin_amdgcn_mfma_f32_16x16x32_bf16(af[m], bu[n], accu[m][n], 0, 0, 0);
        }
    }
  }

  // C/D: col = lane&15, row = fq*4 + j within each 16-row m-frag
#pragma unroll
  for (int m = 0; m < 4; m++) {
    const int rbase = wm * 64 + m * 16 + fq * 4;
#pragma unroll
    for (int j = 0; j < 4; j++) {
      const int rloc = rbase + j;
      const float w = wt[row0 + rloc];
#pragma unroll
      for (int n = 0; n < 2; n++) {
        const float g = accg[m][n][j];
        const float u = accu[m][n][j];
        const float s = g / (1.f + __expf(-g));   // silu
        ACT[(size_t)(row0 + rloc) * II + n0 + (wn * 32 + n * 16 + fr)] = f2bf(s * u * w);
      }
    }
  }
}

// ---------------- GEMM2: D[row][h] = ACT @ Wd ----------------
// Tile 128(M) x 128(N), BK=64, 4 waves as 2x2; gld16 staging (R12/R13 form).
__global__ __launch_bounds__(256) void gemm2_kernel(
    const u16* __restrict__ ACT, const u16* __restrict__ WdT,
    const int* __restrict__ tile_e, const int* __restrict__ tile_r,
    const int* __restrict__ ntiles, u16* __restrict__ D) {
  const int tileid = blockIdx.y;
  if (tileid >= *ntiles) return;
  const int e = tile_e[tileid];
  const int row0 = tile_r[tileid];
  const int n0 = blockIdx.x * 128;

  __shared__ __align__(16) u16 As[128 * 64];   // 16 KB
  __shared__ __align__(16) u16 Bs[128 * 64];   // 16 KB

  const int tid = threadIdx.x;
  const int lane = tid & 63;
  const int wid = tid >> 6;
  const int wm = wid >> 1, wn = wid & 1;
  const int fr = lane & 15, fq = lane >> 4;

  const int lrow = lane >> 3;
  const int sc8 = ((lane & 7) ^ lrow) * 8;

  const u16 *gA[4], *gB[4];
  u16 *lA[4], *lB[4];
#pragma unroll
  for (int j = 0; j < 4; j++) {
    const int trow = j * 32 + wid * 8 + lrow;
    gA[j] = ACT + (size_t)(row0 + trow) * II + sc8;
    gB[j] = WdT + ((size_t)e * HH + n0 + trow) * II + sc8;
    lA[j] = As + (j * 4 + wid) * 512;
    lB[j] = Bs + (j * 4 + wid) * 512;
  }

  f32x4 acc[4][4];
  const f32x4 vz = {0.f, 0.f, 0.f, 0.f};
#pragma unroll
  for (int m = 0; m < 4; m++)
#pragma unroll
    for (int n = 0; n < 4; n++) acc[m][n] = vz;

  for (int k0 = 0; k0 < II; k0 += 64) {
    __syncthreads();
#pragma unroll
    for (int j = 0; j < 4; j++) { gld16(gA[j] + k0, lA[j]); gld16(gB[j] + k0, lB[j]); }
    __syncthreads();

#pragma unroll
    for (int ks = 0; ks < 2; ks++) {
      short8 af[4], bf[4];
#pragma unroll
      for (int m = 0; m < 4; m++) {
        const int r = wm * 64 + m * 16 + fr;
        af[m] = *(const short8*)(&As[r * 64 + (((ks * 4 + fq) ^ (r & 7)) * 8)]);
      }
#pragma unroll
      for (int n = 0; n < 4; n++) {
        const int r = wn * 64 + n * 16 + fr;
        bf[n] = *(const short8*)(&Bs[r * 64 + (((ks * 4 + fq) ^ (r & 7)) * 8)]);
      }
#pragma unroll
      for (int m = 0; m < 4; m++)
#pragma unroll
        for (int n = 0; n < 4; n++)
          acc[m][n] = __builtin_amdgcn_mfma_f32_16x16x32_bf16(af[m], bf[n], acc[m][n], 0, 0, 0);
    }
  }

#pragma unroll
  for (int m = 0; m < 4; m++) {
    const int rbase = wm * 64 + m * 16 + fq * 4;
#pragma unroll
    for (int j = 0; j < 4; j++) {
      u16* dp = D + (size_t)(row0 + rbase + j) * HH + n0 + wn * 64 + fr;
#pragma unroll
      for (int n = 0; n < 4; n++)
        dp[n * 16] = f2bf(acc[m][n][j]);
    }
  }
}

// ---------------- combine: out[t][h] = sum over t's valid pairs of D[row][h] ----------------
__global__ __launch_bounds__(256) void combine_kernel(
    const u16* __restrict__ D, const int* __restrict__ rowof,
    float* __restrict__ out) {
  const int t = blockIdx.x;
  const int h = threadIdx.x * 4;
  const int4 r4 = ((const int4*)rowof)[t];
  float a0 = 0.f, a1 = 0.f, a2 = 0.f, a3 = 0.f;
#define ACCUM(R)                                                     \
  if ((R) >= 0) {                                                    \
    u16x4 d = *(const u16x4*)(D + (size_t)(R) * HH + h);             \
    a0 += bf2f(d[0]); a1 += bf2f(d[1]); a2 += bf2f(d[2]); a3 += bf2f(d[3]); \
  }
  ACCUM(r4.x) ACCUM(r4.y) ACCUM(r4.z) ACCUM(r4.w)
#undef ACCUM
  float4 o = { a0, a1, a2, a3 };
  *(float4*)(out + (size_t)t * HH + h) = o;
}

// ---------------- launch ----------------
extern "C" void kernel_launch(void* const* d_in, const int* in_sizes, int n_in,
                              void* d_out, int out_size, void* d_ws, size_t ws_size,
                              hipStream_t stream) {
  const float* x = (const float*)d_in[0];
  const int* tidx = (const int*)d_in[1];
  const float* tw = (const float*)d_in[2];
  const float* wg = (const float*)d_in[3];
  const float* wu = (const float*)d_in[4];
  const float* wd = (const float*)d_in[5];
  float* out = (float*)d_out;

  // ws layout (bytes); D overlays WgT/WuT (dead after gemm1).
  char* ws = (char*)d_ws;
  int* ntiles = (int*)(ws + 0);
  int* tile_e = (int*)(ws + 1024);
  int* tile_r = (int*)(ws + 2048);
  int* perm = (int*)(ws + 4096);                 // 12288 ints
  float* wt = (float*)(ws + 53248);              // 12288 floats
  int* rowof = (int*)(ws + 102400);              // 8192 ints
  u16* xb = (u16*)(ws + 262144);                 // [2048][1024] bf16, 4 MB
  u16* WgT = (u16*)(ws + 4456448);               // [E][I][H] bf16, 16.78 MB
  u16* WuT = (u16*)(ws + 21233664);              // [E][I][H] bf16, 16.78 MB
  u16* WdT = (u16*)(ws + 38010880);              // [E][H][I] bf16, 16.78 MB
  u16* ACT = (u16*)(ws + 54788096);              // [MAXROWS][I] bf16, 12.58 MB
  u16* D = (u16*)(ws + 4456448);                 // [MAXROWS][H] bf16, 25.2 MB (overlay)

  prep_fused<<<897, 1024, 0, stream>>>(x, tidx, tw, wg, wu, wd,
                                       xb, WgT, WuT, WdT,
                                       perm, wt, rowof, tile_e, tile_r, ntiles);
  gemm1_kernel<<<dim3(II / 64, 80), 256, 0, stream>>>(xb, WgT, WuT, perm, wt,
                                                      tile_e, tile_r, ntiles, ACT);
  gemm2_kernel<<<dim3(HH / 128, 80), 256, 0, stream>>>(ACT, WdT,
                                                       tile_e, tile_r, ntiles, D);
  combine_kernel<<<TT, 256, 0, stream>>>(D, rowof, out);
}

// Round 16
// 78.424 us; speedup vs baseline: 1.0734x; 1.0071x over previous
//
#include <hip/hip_runtime.h>
#include <hip/hip_bf16.h>
#include <stdint.h>

// Problem constants: B=1, S=2048, H=1024, I=512, E=16, K=4
#define HH 1024
#define II 512
#define EE 16
#define TT 2048
#define KTOP 4
#define PP (TT * KTOP)      // 8192 routed pairs
#define MAXROWS 12288       // padded row capacity

typedef unsigned short u16;
typedef unsigned int u32;
typedef __attribute__((ext_vector_type(8))) short short8;       // bf16 MFMA A/B frag
typedef __attribute__((ext_vector_type(4))) float f32x4;        // MFMA C/D frag
typedef __attribute__((ext_vector_type(4))) unsigned short u16x4;
typedef __attribute__((ext_vector_type(8))) unsigned short u16x8;
typedef __attribute__((ext_vector_type(4))) unsigned int u32x4;

__device__ __forceinline__ u16 f2bf(float f) {  // fp32 -> bf16 RNE
  union { float f; unsigned u; } v; v.f = f;
  unsigned r = v.u + 0x7fffu + ((v.u >> 16) & 1u);
  return (u16)(r >> 16);
}
__device__ __forceinline__ float bf2f(u16 b) {
  union { unsigned u; float f; } v; v.u = ((unsigned)b) << 16; return v.f;
}
__device__ __forceinline__ u32 packbf(float lo, float hi) {
  return (u32)f2bf(lo) | ((u32)f2bf(hi) << 16);
}

// Direct global->LDS DMA, 16B per lane; dest wave-uniform base + lane*16.
__device__ __forceinline__ void gld16(const u16* g, u16* l) {
  __builtin_amdgcn_global_load_lds(
      (const __attribute__((address_space(1))) unsigned int*)g,
      (__attribute__((address_space(3))) unsigned int*)l, 16, 0, 0);
}

// ================= fused prep =================
// 641 blocks x 1024 threads:
//   block 0        : routing (16 waves, proven form)
//   blocks 1..128  : x fp32 -> bf16
//   blocks 129..640: Wg+Wu+Wd transpose, one 128x128 fp32 tile of EACH per
//                    block, 2-buffer / 3-phase LDS pipeline (R14 pattern +
//                    third phase). R13-verified swizzle. 1 grid round.
union PLds {
  int s_e[PP];               // 32 KB routing state
  u32 t2[2][128][68];        // 69.6 KB transpose dbuf
};

__global__ __launch_bounds__(1024) void prep_fused(
    const float* __restrict__ x, const int* __restrict__ tidx,
    const float* __restrict__ tw,
    const float* __restrict__ wg, const float* __restrict__ wu,
    const float* __restrict__ wd,
    u16* __restrict__ xb, u16* __restrict__ WgT, u16* __restrict__ WuT,
    u16* __restrict__ WdT,
    int* __restrict__ perm, float* __restrict__ wt, int* __restrict__ rowof,
    int* __restrict__ tile_e, int* __restrict__ tile_r,
    int* __restrict__ ntiles) {
  __shared__ PLds L;
  __shared__ int whist[16][16];
  __shared__ int wbase[16][16];
  __shared__ int pad_lo[EE], pad_hi[EE];

  const int bid = blockIdx.x;
  const int tid = threadIdx.x;

  if (bid == 0) {
    // ---------------- routing (16 waves x 512-pair segments) ----------------
    const int lane = tid & 63;
    const int wv = tid >> 6;

#pragma unroll
    for (int i = 0; i < 2; i++) {
      const int t = tid + i * 1024;
      const int4 v = ((const int4*)tidx)[t];
      const bool v0 = (v.x != v.y) && (v.x != v.z) && (v.x != v.w);
      const bool v1 = (v.y != v.z) && (v.y != v.w);
      const bool v2 = (v.z != v.w);
      L.s_e[t * 4 + 0] = v.x | (v0 ? 16 : 0);
      L.s_e[t * 4 + 1] = v.y | (v1 ? 16 : 0);
      L.s_e[t * 4 + 2] = v.z | (v2 ? 16 : 0);
      L.s_e[t * 4 + 3] = v.w | 16;
    }
    __syncthreads();

    int h0, h1, h2, h3, h4, h5, h6, h7, h8, h9, h10, h11, h12, h13, h14, h15;
    h0=h1=h2=h3=h4=h5=h6=h7=h8=h9=h10=h11=h12=h13=h14=h15=0;
    const unsigned long long ltm = (1ull << lane) - 1ull;
    for (int c = 0; c < 8; c++) {
      const int p = (wv << 9) + (c << 6) + lane;
      const int se = L.s_e[p];
      const int e = se & 15;
      const bool valid = (se & 16) != 0;
      int rank = 0;
#define RANK_STEP(J, HJ)                                            \
      {                                                             \
        unsigned long long m = __ballot(valid && (e == J));         \
        if (valid && (e == J)) rank = HJ + __popcll(m & ltm);       \
        HJ += __popcll(m);                                          \
      }
      RANK_STEP(0, h0)  RANK_STEP(1, h1)  RANK_STEP(2, h2)  RANK_STEP(3, h3)
      RANK_STEP(4, h4)  RANK_STEP(5, h5)  RANK_STEP(6, h6)  RANK_STEP(7, h7)
      RANK_STEP(8, h8)  RANK_STEP(9, h9)  RANK_STEP(10, h10) RANK_STEP(11, h11)
      RANK_STEP(12, h12) RANK_STEP(13, h13) RANK_STEP(14, h14) RANK_STEP(15, h15)
#undef RANK_STEP
      if (valid) L.s_e[p] = se | (rank << 16);
    }
    if (lane == 0) {
      whist[wv][0] = h0;   whist[wv][1] = h1;   whist[wv][2] = h2;   whist[wv][3] = h3;
      whist[wv][4] = h4;   whist[wv][5] = h5;   whist[wv][6] = h6;   whist[wv][7] = h7;
      whist[wv][8] = h8;   whist[wv][9] = h9;   whist[wv][10] = h10; whist[wv][11] = h11;
      whist[wv][12] = h12; whist[wv][13] = h13; whist[wv][14] = h14; whist[wv][15] = h15;
    }
    __syncthreads();

    if (tid == 0) {
      int off = 0, nt = 0;
      for (int j = 0; j < EE; j++) {
        int tot = 0;
        for (int w = 0; w < 16; w++) { wbase[w][j] = off + tot; tot += whist[w][j]; }
        const int cap = (tot + 127) & ~127;
        pad_lo[j] = off + tot;
        pad_hi[j] = off + cap;
        for (int m0 = 0; m0 < cap; m0 += 128) { tile_e[nt] = j; tile_r[nt] = off + m0; nt++; }
        off += cap;
      }
      *ntiles = nt;
    }
    __syncthreads();

#pragma unroll
    for (int i = 0; i < 8; i++) {
      const int p = i * 1024 + tid;
      const int se = L.s_e[p];
      int pos = -1;
      if (se & 16) {
        const int e = se & 15;
        const int r = se >> 16;
        pos = wbase[p >> 9][e] + r;
        perm[pos] = p >> 2;
        wt[pos] = tw[p];
      }
      rowof[p] = pos;
    }
    for (int j = 0; j < EE; j++) {
      const int lo = pad_lo[j], hi = pad_hi[j];
      for (int i = lo + tid; i < hi; i += 1024) {
        perm[i] = 0;          // pad: token 0 with weight 0 contributes nothing
        wt[i] = 0.f;
      }
    }
    return;
  }

  if (bid <= 128) {
    // ---------------- x fp32 -> bf16, 16 elems/thread ----------------
    const int base = ((bid - 1) * 1024 + tid) * 16;
    f32x4 v0 = *(const f32x4*)(x + base);
    f32x4 v1 = *(const f32x4*)(x + base + 4);
    f32x4 v2 = *(const f32x4*)(x + base + 8);
    f32x4 v3 = *(const f32x4*)(x + base + 12);
    u16x8 o0 = { f2bf(v0[0]), f2bf(v0[1]), f2bf(v0[2]), f2bf(v0[3]),
                 f2bf(v1[0]), f2bf(v1[1]), f2bf(v1[2]), f2bf(v1[3]) };
    u16x8 o1 = { f2bf(v2[0]), f2bf(v2[1]), f2bf(v2[2]), f2bf(v2[3]),
                 f2bf(v3[0]), f2bf(v3[1]), f2bf(v3[2]), f2bf(v3[3]) };
    *(u16x8*)(xb + base) = o0;
    *(u16x8*)(xb + base + 8) = o1;
    return;
  }

  // -------- Wg+Wu+Wd transpose: one 128x128 fp32 tile of each, 3-phase --------
  const int pb = bid - 129;              // 0..511
  const int zz = pb >> 5;                // expert
  const int sub = pb & 31;
  const size_t mat = (size_t)zz * HH * II;
  // Wg/Wu geometry: rows=h (HH), cols=i (II): 8 x 4 tiles
  const int r0 = (sub >> 2) * 128, c0 = (sub & 3) * 128;
  // Wd geometry: rows=i (II), cols=h (HH): 4 x 8 tiles
  const int r0d = (sub >> 3) * 128, c0d = (sub & 7) * 128;

  const int rp = tid >> 4, cq8 = (tid & 15) * 8;
  const float* spG = wg + mat + (size_t)(r0 + 2 * rp) * II + c0 + cq8;
  const float* spU = wu + mat + (size_t)(r0 + 2 * rp) * II + c0 + cq8;
  const float* spD = wd + mat + (size_t)(r0d + 2 * rp) * HH + c0d + cq8;

  // phase-0 loads: Wg + Wu, all 16 issued up front, pinned
  const f32x4 ga0 = *(const f32x4*)(spG);
  const f32x4 ga1 = *(const f32x4*)(spG + 4);
  const f32x4 gb0 = *(const f32x4*)(spG + II);
  const f32x4 gb1 = *(const f32x4*)(spG + II + 4);
  const f32x4 ua0 = *(const f32x4*)(spU);
  const f32x4 ua1 = *(const f32x4*)(spU + 4);
  const f32x4 ub0 = *(const f32x4*)(spU + II);
  const f32x4 ub1 = *(const f32x4*)(spU + II + 4);
  __builtin_amdgcn_sched_barrier(0);

  // swizzle coords (R13-verified)
  const int key = tid & 15;
  const int rpx = rp ^ ((key & 7) << 3) ^ (((key >> 2) & 1) << 2);
  const int c = tid >> 3, q = tid & 7;
  const int rkey = c >> 3;
  const int qb = (q ^ (rkey & 7)) * 8;
  const int b2 = ((rkey >> 2) & 1) * 4;
  const size_t doffGU = mat + (size_t)(c0 + c) * HH + r0 + q * 16;
  const size_t doffD  = mat + (size_t)(c0d + c) * II + r0d + q * 16;

  // phase 0: write Wg -> buf0
#pragma unroll
  for (int j = 0; j < 4; j++) L.t2[0][cq8 + j][rpx] = packbf(ga0[j], gb0[j]);
#pragma unroll
  for (int j = 0; j < 4; j++) L.t2[0][cq8 + 4 + j][rpx] = packbf(ga1[j], gb1[j]);
  __syncthreads();

  // phase 1: store WgT from buf0 | issue Wd loads | write Wu -> buf1
  const f32x4 da0 = *(const f32x4*)(spD);
  const f32x4 da1 = *(const f32x4*)(spD + 4);
  const f32x4 db0 = *(const f32x4*)(spD + HH);
  const f32x4 db1 = *(const f32x4*)(spD + HH + 4);
  __builtin_amdgcn_sched_barrier(0);
  {
    u32x4 v0, v1;
#pragma unroll
    for (int j = 0; j < 4; j++) v0[j] = L.t2[0][c][qb + b2 + j];
#pragma unroll
    for (int j = 0; j < 4; j++) v1[j] = L.t2[0][c][qb + (b2 ^ 4) + j];
    u16* dp = WgT + doffGU;
    *(u32x4*)(dp) = v0;
    *(u32x4*)(dp + 8) = v1;
  }
#pragma unroll
  for (int j = 0; j < 4; j++) L.t2[1][cq8 + j][rpx] = packbf(ua0[j], ub0[j]);
#pragma unroll
  for (int j = 0; j < 4; j++) L.t2[1][cq8 + 4 + j][rpx] = packbf(ua1[j], ub1[j]);
  __syncthreads();

  // phase 2: store WuT from buf1 | write Wd -> buf0
  {
    u32x4 v0, v1;
#pragma unroll
    for (int j = 0; j < 4; j++) v0[j] = L.t2[1][c][qb + b2 + j];
#pragma unroll
    for (int j = 0; j < 4; j++) v1[j] = L.t2[1][c][qb + (b2 ^ 4) + j];
    u16* dp = WuT + doffGU;
    *(u32x4*)(dp) = v0;
    *(u32x4*)(dp + 8) = v1;
  }
#pragma unroll
  for (int j = 0; j < 4; j++) L.t2[0][cq8 + j][rpx] = packbf(da0[j], db0[j]);
#pragma unroll
  for (int j = 0; j < 4; j++) L.t2[0][cq8 + 4 + j][rpx] = packbf(da1[j], db1[j]);
  __syncthreads();

  // phase 3: store WdT from buf0
  {
    u32x4 v0, v1;
#pragma unroll
    for (int j = 0; j < 4; j++) v0[j] = L.t2[0][c][qb + b2 + j];
#pragma unroll
    for (int j = 0; j < 4; j++) v1[j] = L.t2[0][c][qb + (b2 ^ 4) + j];
    u16* dp = WdT + doffD;
    *(u32x4*)(dp) = v0;
    *(u32x4*)(dp + 8) = v1;
  }
}

// ---------------- GEMM1: ACT[r][i] = silu(x@Wg) * (x@Wu) * gate_weight ----------------
// Tile 128(M) x 64(N), BK=64, 4 waves as 2x2. gld16 staging (R12/R13-verified).
__global__ __launch_bounds__(256) void gemm1_kernel(
    const u16* __restrict__ xb, const u16* __restrict__ WgT, const u16* __restrict__ WuT,
    const int* __restrict__ perm, const float* __restrict__ wt,
    const int* __restrict__ tile_e, const int* __restrict__ tile_r,
    const int* __restrict__ ntiles, u16* __restrict__ ACT) {
  const int tileid = blockIdx.y;
  if (tileid >= *ntiles) return;
  const int e = tile_e[tileid];
  const int row0 = tile_r[tileid];
  const int n0 = blockIdx.x * 64;

  __shared__ __align__(16) u16 As[128 * 64];   // 16 KB
  __shared__ __align__(16) u16 Gs[64 * 64];    // 8 KB
  __shared__ __align__(16) u16 Us[64 * 64];    // 8 KB

  const int tid = threadIdx.x;
  const int lane = tid & 63;
  const int wid = tid >> 6;
  const int wm = wid >> 1, wn = wid & 1;
  const int fr = lane & 15, fq = lane >> 4;

  const int lrow = lane >> 3;            // 0..7: row within 8-row group
  const int sc8 = ((lane & 7) ^ lrow) * 8;  // pre-swizzled global chunk (u16 units)

  const u16* gA[4]; u16* lA[4];
#pragma unroll
  for (int j = 0; j < 4; j++) {
    const int trow = j * 32 + wid * 8 + lrow;
    gA[j] = xb + (size_t)perm[row0 + trow] * HH + sc8;
    lA[j] = As + (j * 4 + wid) * 512;
  }
  const u16 *gG[2], *gU[2];
  u16 *lG[2], *lU[2];
#pragma unroll
  for (int j = 0; j < 2; j++) {
    const int nrow = j * 32 + wid * 8 + lrow;
    gG[j] = WgT + ((size_t)e * II + n0 + nrow) * HH + sc8;
    gU[j] = WuT + ((size_t)e * II + n0 + nrow) * HH + sc8;
    lG[j] = Gs + (j * 4 + wid) * 512;
    lU[j] = Us + (j * 4 + wid) * 512;
  }

  f32x4 accg[4][2], accu[4][2];
  const f32x4 vz = {0.f, 0.f, 0.f, 0.f};
#pragma unroll
  for (int m = 0; m < 4; m++)
#pragma unroll
    for (int n = 0; n < 2; n++) { accg[m][n] = vz; accu[m][n] = vz; }

  for (int k0 = 0; k0 < HH; k0 += 64) {
    __syncthreads();
#pragma unroll
    for (int j = 0; j < 4; j++) gld16(gA[j] + k0, lA[j]);
#pragma unroll
    for (int j = 0; j < 2; j++) { gld16(gG[j] + k0, lG[j]); gld16(gU[j] + k0, lU[j]); }
    __syncthreads();

#pragma unroll
    for (int ks = 0; ks < 2; ks++) {
      short8 af[4], bg[2], bu[2];
#pragma unroll
      for (int m = 0; m < 4; m++) {
        const int r = wm * 64 + m * 16 + fr;
        af[m] = *(const short8*)(&As[r * 64 + (((ks * 4 + fq) ^ (r & 7)) * 8)]);
      }
#pragma unroll
      for (int n = 0; n < 2; n++) {
        const int r = wn * 32 + n * 16 + fr;
        bg[n] = *(const short8*)(&Gs[r * 64 + (((ks * 4 + fq) ^ (r & 7)) * 8)]);
        bu[n] = *(const short8*)(&Us[r * 64 + (((ks * 4 + fq) ^ (r & 7)) * 8)]);
      }
#pragma unroll
      for (int m = 0; m < 4; m++)
#pragma unroll
        for (int n = 0; n < 2; n++) {
          accg[m][n] = __builtin_amdgcn_mfma_f32_16x16x32_bf16(af[m], bg[n], accg[m][n], 0, 0, 0);
          accu[m][n] = __builtin_amdgcn_mfma_f32_16x16x32_bf16(af[m], bu[n], accu[m][n], 0, 0, 0);
        }
    }
  }

  // C/D: col = lane&15, row = fq*4 + j within each 16-row m-frag
#pragma unroll
  for (int m = 0; m < 4; m++) {
    const int rbase = wm * 64 + m * 16 + fq * 4;
#pragma unroll
    for (int j = 0; j < 4; j++) {
      const int rloc = rbase + j;
      const float w = wt[row0 + rloc];
#pragma unroll
      for (int n = 0; n < 2; n++) {
        const float g = accg[m][n][j];
        const float u = accu[m][n][j];
        const float s = g / (1.f + __expf(-g));   // silu
        ACT[(size_t)(row0 + rloc) * II + n0 + (wn * 32 + n * 16 + fr)] = f2bf(s * u * w);
      }
    }
  }
}

// ---------------- GEMM2: D[row][h] = ACT @ Wd ----------------
// Tile 128(M) x 128(N), BK=64, 4 waves as 2x2; gld16 staging (R12/R13 form).
__global__ __launch_bounds__(256) void gemm2_kernel(
    const u16* __restrict__ ACT, const u16* __restrict__ WdT,
    const int* __restrict__ tile_e, const int* __restrict__ tile_r,
    const int* __restrict__ ntiles, u16* __restrict__ D) {
  const int tileid = blockIdx.y;
  if (tileid >= *ntiles) return;
  const int e = tile_e[tileid];
  const int row0 = tile_r[tileid];
  const int n0 = blockIdx.x * 128;

  __shared__ __align__(16) u16 As[128 * 64];   // 16 KB
  __shared__ __align__(16) u16 Bs[128 * 64];   // 16 KB

  const int tid = threadIdx.x;
  const int lane = tid & 63;
  const int wid = tid >> 6;
  const int wm = wid >> 1, wn = wid & 1;
  const int fr = lane & 15, fq = lane >> 4;

  const int lrow = lane >> 3;
  const int sc8 = ((lane & 7) ^ lrow) * 8;

  const u16 *gA[4], *gB[4];
  u16 *lA[4], *lB[4];
#pragma unroll
  for (int j = 0; j < 4; j++) {
    const int trow = j * 32 + wid * 8 + lrow;
    gA[j] = ACT + (size_t)(row0 + trow) * II + sc8;
    gB[j] = WdT + ((size_t)e * HH + n0 + trow) * II + sc8;
    lA[j] = As + (j * 4 + wid) * 512;
    lB[j] = Bs + (j * 4 + wid) * 512;
  }

  f32x4 acc[4][4];
  const f32x4 vz = {0.f, 0.f, 0.f, 0.f};
#pragma unroll
  for (int m = 0; m < 4; m++)
#pragma unroll
    for (int n = 0; n < 4; n++) acc[m][n] = vz;

  for (int k0 = 0; k0 < II; k0 += 64) {
    __syncthreads();
#pragma unroll
    for (int j = 0; j < 4; j++) { gld16(gA[j] + k0, lA[j]); gld16(gB[j] + k0, lB[j]); }
    __syncthreads();

#pragma unroll
    for (int ks = 0; ks < 2; ks++) {
      short8 af[4], bf[4];
#pragma unroll
      for (int m = 0; m < 4; m++) {
        const int r = wm * 64 + m * 16 + fr;
        af[m] = *(const short8*)(&As[r * 64 + (((ks * 4 + fq) ^ (r & 7)) * 8)]);
      }
#pragma unroll
      for (int n = 0; n < 4; n++) {
        const int r = wn * 64 + n * 16 + fr;
        bf[n] = *(const short8*)(&Bs[r * 64 + (((ks * 4 + fq) ^ (r & 7)) * 8)]);
      }
#pragma unroll
      for (int m = 0; m < 4; m++)
#pragma unroll
        for (int n = 0; n < 4; n++)
          acc[m][n] = __builtin_amdgcn_mfma_f32_16x16x32_bf16(af[m], bf[n], acc[m][n], 0, 0, 0);
    }
  }

#pragma unroll
  for (int m = 0; m < 4; m++) {
    const int rbase = wm * 64 + m * 16 + fq * 4;
#pragma unroll
    for (int j = 0; j < 4; j++) {
      u16* dp = D + (size_t)(row0 + rbase + j) * HH + n0 + wn * 64 + fr;
#pragma unroll
      for (int n = 0; n < 4; n++)
        dp[n * 16] = f2bf(acc[m][n][j]);
    }
  }
}

// ---------------- combine: out[t][h] = sum over t's valid pairs of D[row][h] ----------------
__global__ __launch_bounds__(256) void combine_kernel(
    const u16* __restrict__ D, const int* __restrict__ rowof,
    float* __restrict__ out) {
  const int t = blockIdx.x;
  const int h = threadIdx.x * 4;
  const int4 r4 = ((const int4*)rowof)[t];
  float a0 = 0.f, a1 = 0.f, a2 = 0.f, a3 = 0.f;
#define ACCUM(R)                                                     \
  if ((R) >= 0) {                                                    \
    u16x4 d = *(const u16x4*)(D + (size_t)(R) * HH + h);             \
    a0 += bf2f(d[0]); a1 += bf2f(d[1]); a2 += bf2f(d[2]); a3 += bf2f(d[3]); \
  }
  ACCUM(r4.x) ACCUM(r4.y) ACCUM(r4.z) ACCUM(r4.w)
#undef ACCUM
  float4 o = { a0, a1, a2, a3 };
  *(float4*)(out + (size_t)t * HH + h) = o;
}

// ---------------- launch ----------------
extern "C" void kernel_launch(void* const* d_in, const int* in_sizes, int n_in,
                              void* d_out, int out_size, void* d_ws, size_t ws_size,
                              hipStream_t stream) {
  const float* x = (const float*)d_in[0];
  const int* tidx = (const int*)d_in[1];
  const float* tw = (const float*)d_in[2];
  const float* wg = (const float*)d_in[3];
  const float* wu = (const float*)d_in[4];
  const float* wd = (const float*)d_in[5];
  float* out = (float*)d_out;

  // ws layout (bytes); D overlays WgT/WuT (dead after gemm1).
  char* ws = (char*)d_ws;
  int* ntiles = (int*)(ws + 0);
  int* tile_e = (int*)(ws + 1024);
  int* tile_r = (int*)(ws + 2048);
  int* perm = (int*)(ws + 4096);                 // 12288 ints
  float* wt = (float*)(ws + 53248);              // 12288 floats
  int* rowof = (int*)(ws + 102400);              // 8192 ints
  u16* xb = (u16*)(ws + 262144);                 // [2048][1024] bf16, 4 MB
  u16* WgT = (u16*)(ws + 4456448);               // [E][I][H] bf16, 16.78 MB
  u16* WuT = (u16*)(ws + 21233664);              // [E][I][H] bf16, 16.78 MB
  u16* WdT = (u16*)(ws + 38010880);              // [E][H][I] bf16, 16.78 MB
  u16* ACT = (u16*)(ws + 54788096);              // [MAXROWS][I] bf16, 12.58 MB
  u16* D = (u16*)(ws + 4456448);                 // [MAXROWS][H] bf16, 25.2 MB (overlay)

  prep_fused<<<641, 1024, 0, stream>>>(x, tidx, tw, wg, wu, wd,
                                       xb, WgT, WuT, WdT,
                                       perm, wt, rowof, tile_e, tile_r, ntiles);
  gemm1_kernel<<<dim3(II / 64, 80), 256, 0, stream>>>(xb, WgT, WuT, perm, wt,
                                                      tile_e, tile_r, ntiles, ACT);
  gemm2_kernel<<<dim3(HH / 128, 80), 256, 0, stream>>>(ACT, WdT,
                                                       tile_e, tile_r, ntiles, D);
  combine_kernel<<<TT, 256, 0, stream>>>(D, rowof, out);
}